// Round 10
// baseline (163.802 us; speedup 1.0000x reference)
//
#include <hip/hip_runtime.h>
#include <hip/hip_bf16.h>
#include <math.h>

#define NB 4
#define CC 128
#define HH 64
#define WW 64
#define HEADS 4
#define KS 7
#define DD 32
#define HW 4096
#define MTOT 16384   // NB*HW

typedef unsigned short BF;
typedef short short8 __attribute__((ext_vector_type(8)));
typedef float floatx4 __attribute__((ext_vector_type(4)));

__device__ __forceinline__ float gelu_f(float x) {
    return 0.5f * x * (1.0f + erff(x * 0.70710678118654752440f));
}

__device__ __forceinline__ BF f2bf(float f) {
    union { float f; unsigned u; } a; a.f = f;
    unsigned u = a.u;
    unsigned r = u + 0x7FFFu + ((u >> 16) & 1u);   // RNE
    return (BF)(r >> 16);
}

__device__ __forceinline__ float bf2f(BF v) {
    return __uint_as_float(((unsigned)v) << 16);
}

#define LDK 40      // padded LDS row, K=32 tiles (bf16)

// ---------------- weight prep (bid<128, dispatched FIRST) + LN1 -------
// Prep blocks have the longest path (7-iter grid-stride loop); putting
// them first hides their tail under the 1024-block LN supply (the same
// ordering fix R9 applied to phase2's conv blocks).
__global__ __launch_bounds__(256) void ln1t_kernel(
    const float* __restrict__ x, const float* __restrict__ w,
    const float* __restrict__ b, BF* __restrict__ out,
    float* __restrict__ part,
    const float* __restrict__ qkv_w, const float* __restrict__ conv1_w,
    const float* __restrict__ conv2_w, const float* __restrict__ proj_w,
    const float* __restrict__ fc1_w, const float* __restrict__ fc2_w,
    BF* __restrict__ qkvT, BF* __restrict__ c1T, BF* __restrict__ c2T,
    BF* __restrict__ projT2, BF* __restrict__ fc1T2, BF* __restrict__ fc2T2)
{
    const int blk = blockIdx.x;
    const int t  = threadIdx.x;

    if (blk < 128) {   // ---- weight prep (one-time, 204800 elems) ----
        for (int idx = blk * 256 + t; idx < 204800; idx += 32768) {
            if (idx < 49152) {                    // qkvT [384][128]
                int l = idx, n = l >> 7, k = l & 127;
                qkvT[l] = f2bf(qkv_w[k * 384 + n]);
            } else if (idx < 53248) {             // c1T [32][128]
                int l = idx - 49152, n = l >> 7, k = l & 127;
                c1T[l] = f2bf(conv1_w[k * 32 + n]);
            } else if (idx < 57344) {             // c2T [128][32]
                int l = idx - 53248, n = l >> 5, k = l & 31;
                c2T[l] = f2bf(conv2_w[k * 128 + n]);
            } else if (idx < 73728) {             // projT2 [4][128][32]
                int l = idx - 57344, kk = l & 31, n = (l >> 5) & 127, ks = l >> 12;
                projT2[l] = f2bf(proj_w[(ks * 32 + kk) * 128 + n]);
            } else if (idx < 139264) {            // fc1T2 [4][512][32]
                int l = idx - 73728, kk = l & 31, n = (l >> 5) & 511, ks = l >> 14;
                fc1T2[l] = f2bf(fc1_w[(ks * 32 + kk) * 512 + n]);
            } else {                              // fc2T2 [16][128][32]
                int l = idx - 139264, kk = l & 31, n = (l >> 5) & 127, ks = l >> 12;
                fc2T2[l] = f2bf(fc2_w[(ks * 32 + kk) * 128 + n]);
            }
        }
        return;
    }

    __shared__ float xt[128][17];
    __shared__ float mus[16], rss[16];
    const int lblk = blk - 128;          // 0..1023
    const int n  = lblk >> 8;
    const int p0 = (lblk & 255) * 16;
    if (lblk < 4 && t < 128) part[lblk * CC + t] = 0.f;   // zero CA partials

    {   // stage [128 c][16 p]: 2 float4 per thread
        int c = t >> 1, pp0 = (t & 1) * 8;
        const float* src = x + (size_t)(n * CC + c) * HW + p0 + pp0;
        float4 v0 = *(const float4*)(src);
        float4 v1 = *(const float4*)(src + 4);
        xt[c][pp0 + 0] = v0.x; xt[c][pp0 + 1] = v0.y;
        xt[c][pp0 + 2] = v0.z; xt[c][pp0 + 3] = v0.w;
        xt[c][pp0 + 4] = v1.x; xt[c][pp0 + 5] = v1.y;
        xt[c][pp0 + 6] = v1.z; xt[c][pp0 + 7] = v1.w;
    }
    __syncthreads();
    {   // stats: 16 threads per pixel, 8 channels each
        int pp2 = t >> 4, cb = t & 15;
        float s = 0.f;
        #pragma unroll
        for (int u = 0; u < 8; u++) s += xt[cb + u * 16][pp2];
        s += __shfl_xor(s, 1); s += __shfl_xor(s, 2);
        s += __shfl_xor(s, 4); s += __shfl_xor(s, 8);
        float mu = s * (1.0f / CC);
        float v = 0.f;
        #pragma unroll
        for (int u = 0; u < 8; u++) { float d = xt[cb + u * 16][pp2] - mu; v += d * d; }
        v += __shfl_xor(v, 1); v += __shfl_xor(v, 2);
        v += __shfl_xor(v, 4); v += __shfl_xor(v, 8);
        if (cb == 0) { mus[pp2] = mu; rss[pp2] = rsqrtf(v * (1.0f / CC) + 1e-5f); }
    }
    __syncthreads();
    {   // apply: one short8 per thread (16 px x 16 thr)
        int pp2 = t >> 4, c0 = (t & 15) * 8;
        float mu = mus[pp2], rs = rss[pp2];
        int m = n * HW + p0 + pp2;
        short8 o;
        #pragma unroll
        for (int u = 0; u < 8; u++)
            o[u] = (short)f2bf((xt[c0 + u][pp2] - mu) * rs * w[c0 + u] + b[c0 + u]);
        *(short8*)(out + (size_t)m * CC + c0) = o;
    }
}

// ---------------- phase2: conv-MLP first, then qkv GEMM ---------------
// B-fragments read DIRECT from L2-resident transposed weights (R5's
// K-direct precedent): kills the Bl/W1l/W2l staging phases and their
// barriers. qkv branch now has ZERO block barriers (Ct is per-wave);
// conv branch keeps only the red-reduction barrier (Hl is per-wave
// private -- same wave-synchronous argument as the Ct epilogue, R7).
// smem 26.6 -> 9.2 KB => phase2 runs at the 8-blocks/CU thread ceiling.
__global__ __launch_bounds__(256) void phase2(
    const BF* __restrict__ xn, const BF* __restrict__ qkvT,
    const float* __restrict__ qkv_b, BF* __restrict__ qkv_out,
    const BF* __restrict__ c1T, const float* __restrict__ b1,
    const BF* __restrict__ c2T, const float* __restrict__ b2,
    BF* __restrict__ tout, float* __restrict__ part)
{
    __shared__ __align__(16) char smem[9216];
    const int bid = blockIdx.x;
    const int t = threadIdx.x;
    const int w = t >> 6, lane = t & 63, q = lane >> 4, r16 = lane & 15;

    if (bid >= 256) {
        const int qb = bid - 256;
        BF* Ct = (BF*)smem;                  // [64][72] 9216 B (per-wave 16-row regions)
        const int col0 = (qb % 6) * 64;
        const int row0 = (qb / 6) * 64;
        floatx4 acc[4] = {};
        const BF* arow = xn + (size_t)(row0 + w * 16 + r16) * CC;
        #pragma unroll
        for (int ks = 0; ks < 4; ks++) {
            short8 af = *(const short8*)(arow + ks * 32 + q * 8);
            #pragma unroll
            for (int nt = 0; nt < 4; nt++) {
                short8 bf = *(const short8*)(qkvT
                    + (size_t)(col0 + nt * 16 + r16) * 128 + ks * 32 + q * 8);
                acc[nt] = __builtin_amdgcn_mfma_f32_16x16x32_bf16(af, bf, acc[nt], 0, 0, 0);
            }
        }
        // stage wave's 16x64 tile in its own Ct region (no block barrier)
        #pragma unroll
        for (int nt = 0; nt < 4; nt++) {
            int col = col0 + nt * 16 + r16;
            float bv = qkv_b[col];
            #pragma unroll
            for (int reg = 0; reg < 4; reg++)
                Ct[(w * 16 + q * 4 + reg) * 72 + nt * 16 + r16] = f2bf(acc[nt][reg] + bv);
        }
        // coalesced short8 stores: 2 per thread
        #pragma unroll
        for (int u2 = 0; u2 < 2; u2++) {
            int r = u2 * 8 + (lane >> 3), c0 = (lane & 7) * 8;
            short8 v = *(const short8*)(Ct + (w * 16 + r) * 72 + c0);
            *(short8*)(qkv_out + (size_t)(row0 + w * 16 + r) * 384 + col0 + c0) = v;
        }
        return;
    }
    // ---- conv branch (bid < 256, dispatched first) ----
    BF*    Hl  = (BF*)smem;                  // [64][LDK]  5120 B
    float* red = (float*)(smem + 5120);      // [4][128]   2048 B
    const int row0 = bid * 64;
    floatx4 a1[2] = {};
    const BF* arow = xn + (size_t)(row0 + w * 16 + r16) * CC;
    #pragma unroll
    for (int ks = 0; ks < 4; ks++) {
        short8 af = *(const short8*)(arow + ks * 32 + q * 8);
        #pragma unroll
        for (int nt = 0; nt < 2; nt++) {
            short8 bf = *(const short8*)(c1T
                + (size_t)(nt * 16 + r16) * 128 + ks * 32 + q * 8);
            a1[nt] = __builtin_amdgcn_mfma_f32_16x16x32_bf16(af, bf, a1[nt], 0, 0, 0);
        }
    }
    // Hl rows w*16..w*16+15 written and read by wave w only (wave-sync)
    #pragma unroll
    for (int nt = 0; nt < 2; nt++) {
        int col = nt * 16 + r16;
        float bv = b1[col];
        #pragma unroll
        for (int reg = 0; reg < 4; reg++)
            Hl[(w * 16 + q * 4 + reg) * LDK + col] = f2bf(gelu_f(a1[nt][reg] + bv));
    }
    floatx4 a2[8] = {};
    short8 af2 = *(const short8*)(Hl + (w * 16 + r16) * LDK + q * 8);
    #pragma unroll
    for (int nt = 0; nt < 8; nt++) {
        short8 bf = *(const short8*)(c2T + (size_t)(nt * 16 + r16) * 32 + q * 8);
        a2[nt] = __builtin_amdgcn_mfma_f32_16x16x32_bf16(af2, bf, a2[nt], 0, 0, 0);
    }
    #pragma unroll
    for (int nt = 0; nt < 8; nt++) {
        int col = nt * 16 + r16;
        float bv = b2[col];
        float s = 0.f;
        #pragma unroll
        for (int reg = 0; reg < 4; reg++) {
            int row = row0 + w * 16 + q * 4 + reg;
            float v = a2[nt][reg] + bv;
            tout[(size_t)row * CC + col] = f2bf(v);
            s += v;
        }
        s += __shfl_xor(s, 16);
        s += __shfl_xor(s, 32);
        if (lane < 16) red[w * 128 + col] = s;
    }
    __syncthreads();
    if (t < 128) {
        float cs = red[t] + red[128 + t] + red[256 + t] + red[384 + t];
        atomicAdd(&part[(row0 >> 12) * CC + t], cs);
    }
}

// ---------------- MFMA neighborhood attention (windowed Pl) -----------
// K/Q direct from L2. Pl stores only the wave's 10-key-tile window
// relative to pbase = kt0 & ~1. LDS 37.1 KB => 4 blocks/CU.
// Block 1024 (extra): per-image CA micro-MLP (gl[4][128]).
__global__ __launch_bounds__(256, 4) void na_mfma_kernel(
    const BF* __restrict__ qkv, const float* __restrict__ rpb,
    BF* __restrict__ outp,
    const float* __restrict__ part,
    const float* __restrict__ ca1_w, const float* __restrict__ ca1_b,
    const float* __restrict__ ca2_w, const float* __restrict__ ca2_b,
    float* __restrict__ glw)
{
    __shared__ __align__(16) BF Vt[32][232];        // 14848 B
    __shared__ __align__(16) BF Pl[4][16][168];     // 21504 B (10-tile window)
    __shared__ float rb[169];

    const int b = blockIdx.x;
    const int t = threadIdx.x;

    if (b == 1024) {   // ---- CA micro-MLP, once per launch ----
        float* gsm = (float*)Vt;    // [4][128] f32, aliases Vt
        float* h1s = (float*)Pl;    // [28] f32, aliases Pl
        if (t < 128) {
            #pragma unroll
            for (int nn = 0; nn < 4; nn++)
                gsm[nn * 128 + t] = part[nn * CC + t] * (1.0f / HW);
        }
        __syncthreads();
        if (t < 224) {              // 28 (n,r) pairs x 8 lanes each
            int pair = t >> 3, s = t & 7;
            int nn = pair / 7, r = pair % 7;
            float a = 0.f;
            #pragma unroll
            for (int k = 0; k < 16; k++)
                a += gsm[nn * 128 + s + k * 8] * ca1_w[(s + k * 8) * 7 + r];
            a += __shfl_xor(a, 1); a += __shfl_xor(a, 2); a += __shfl_xor(a, 4);
            if (s == 0) h1s[pair] = fmaxf(a + ca1_b[r], 0.f);
        }
        __syncthreads();
        if (t < 128) {
            #pragma unroll
            for (int nn = 0; nn < 4; nn++) {
                float o = ca2_b[t];
                #pragma unroll
                for (int r = 0; r < 7; r++) o += h1s[nn * 7 + r] * ca2_w[r * 128 + t];
                glw[nn * CC + t] = 1.0f / (1.0f + expf(-o));
            }
        }
        return;
    }

    const int h = b & 3;
    const int tile = b >> 2;
    const int n = tile >> 6;
    const int ti = (tile >> 3) & 7, tj = tile & 7;
    const int w = t >> 6, lane = t & 63, quad = lane >> 4, r16 = lane & 15;
    const int i0 = ti * 8, j0 = tj * 8;
    const int wi0 = max(i0 - 3, 0), wj0 = max(j0 - 3, 0);
    const int R  = min(wi0 + 13, 63) - wi0 + 1;
    const int Rj = min(wj0 + 13, 63) - wj0 + 1;

    // ---- stage rpb + V (transposed); no barrier yet ----
    if (t < 169) rb[t] = rpb[h * 169 + t];
    for (int idx = t; idx < 896; idx += 256) {
        int key = idx >> 2, ch = idx & 3;
        int kr = key >> 4, kc = key & 15;
        if (kr < R && kc < Rj) {
            size_t pix = (size_t)((n * HH + wi0 + kr) * WW + wj0 + kc);
            uint4 v = *(const uint4*)(qkv + pix * 384 + 256 + h * DD + ch * 8);
            const BF* pv = (const BF*)&v;
            #pragma unroll
            for (int u = 0; u < 8; u++) Vt[ch * 8 + u][key] = pv[u];
        } else {
            #pragma unroll
            for (int u = 0; u < 8; u++) Vt[ch * 8 + u][key] = 0;
        }
    }

    // wave's first pixel row -> pruned k-tile base
    const int kt0 = min(max(i0 + 2 * w - 3, 0), HH - KS) - wi0;
    const int odd = kt0 & 1;     // P window offset: pbase = kt0 - odd

    int oi[4], cok[4], bj0[4], ai_[4];
    #pragma unroll
    for (int reg = 0; reg < 4; reg++) {
        int q = w * 16 + quad * 4 + reg;
        int i = i0 + (q >> 3), j = j0 + (q & 7);
        int ni = min(max(i - 3, 0), HH - KS), nj = min(max(j - 3, 0), WW - KS);
        oi[reg]  = ni - wi0;
        ai_[reg] = ni - i + 6;
        int dc = r16 - (nj - wj0);
        cok[reg] = ((unsigned)dc < 7u) ? 1 : 0;
        bj0[reg] = min(max(dc + (nj - j + 6), 0), 12);
    }

    // ---- Q fragment direct from L2 ----
    const int qr = w * 16 + r16;
    short8 aq = *(const short8*)(qkv
        + (size_t)((n * HH + i0 + (qr >> 3)) * WW + j0 + (qr & 7)) * 384
        + h * DD + quad * 8);

    // ---- QK^T: K fragments direct from L2 (kr=kt0+jt uniform, kc=r16) ----
    floatx4 S[8];
    const bool colok = (r16 < Rj);
    #pragma unroll
    for (int jt = 0; jt < 8; jt++) {
        short8 bk = {0, 0, 0, 0, 0, 0, 0, 0};
        if ((kt0 + jt) < R && colok) {
            bk = *(const short8*)(qkv
                + (size_t)((n * HH + wi0 + kt0 + jt) * WW + wj0 + r16) * 384
                + 128 + h * DD + quad * 8);
        }
        floatx4 z = {0.f, 0.f, 0.f, 0.f};
        S[jt] = __builtin_amdgcn_mfma_f32_16x16x32_bf16(aq, bk, z, 0, 0, 0);
    }
    __syncthreads();   // Vt + rb ready (drained while MFMAs ran)

    const float scale = 0.17677669529663688110f;
    #pragma unroll
    for (int jt = 0; jt < 8; jt++) {
        #pragma unroll
        for (int reg = 0; reg < 4; reg++) {
            int dr = kt0 + jt - oi[reg];
            bool ok = ((unsigned)dr < 7u) && cok[reg];
            int bi = min(max(dr + ai_[reg], 0), 12);
            float bias = rb[bi * 13 + bj0[reg]];
            S[jt][reg] = ok ? fmaf(S[jt][reg], scale, bias) : -1e30f;
        }
    }
    float rinv[4];
    #pragma unroll
    for (int reg = 0; reg < 4; reg++) {
        float m = S[0][reg];
        #pragma unroll
        for (int jt = 1; jt < 8; jt++) m = fmaxf(m, S[jt][reg]);
        m = fmaxf(m, __shfl_xor(m, 1));
        m = fmaxf(m, __shfl_xor(m, 2));
        m = fmaxf(m, __shfl_xor(m, 4));
        m = fmaxf(m, __shfl_xor(m, 8));
        float s = 0.f;
        #pragma unroll
        for (int jt = 0; jt < 8; jt++) {
            float e = __expf(S[jt][reg] - m);
            S[jt][reg] = e;
            s += e;
        }
        s += __shfl_xor(s, 1);
        s += __shfl_xor(s, 2);
        s += __shfl_xor(s, 4);
        s += __shfl_xor(s, 8);
        rinv[reg] = 1.0f / s;
    }
    // Pl is per-wave private; window-relative column (jt+odd)*16 + r16
    #pragma unroll
    for (int jt = 0; jt < 8; jt++)
        #pragma unroll
        for (int reg = 0; reg < 4; reg++)
            Pl[w][quad * 4 + reg][(jt + odd) * 16 + r16] = f2bf(S[jt][reg] * rinv[reg]);
    if (odd) {   // zero boundary tiles 0 and 9 read by the extra PV chunk
        #pragma unroll
        for (int reg = 0; reg < 4; reg++) {
            Pl[w][quad * 4 + reg][r16]            = 0;
            Pl[w][quad * 4 + reg][144 + r16]      = 0;
        }
    }

    const int ks0 = kt0 >> 1;
    const int nch = 4 + odd;
    floatx4 O0 = {0.f, 0.f, 0.f, 0.f}, O1 = {0.f, 0.f, 0.f, 0.f};
    #pragma unroll
    for (int c2 = 0; c2 < 5; c2++) {
        if (c2 < nch) {
            int ks = ks0 + c2;   // absolute (for Vt); Pl col is relative
            short8 ap = *(const short8*)&Pl[w][r16][c2 * 32 + quad * 8];
            short8 b0 = *(const short8*)&Vt[r16][ks * 32 + quad * 8];
            short8 b1 = *(const short8*)&Vt[16 + r16][ks * 32 + quad * 8];
            O0 = __builtin_amdgcn_mfma_f32_16x16x32_bf16(ap, b0, O0, 0, 0, 0);
            O1 = __builtin_amdgcn_mfma_f32_16x16x32_bf16(ap, b1, O1, 0, 0, 0);
        }
    }
    // ---- coalesced output: stage 16x32 tile in Pl[w] (dead after PV) ----
    #pragma unroll
    for (int reg = 0; reg < 4; reg++) {
        Pl[w][quad * 4 + reg][r16]      = f2bf(O0[reg]);
        Pl[w][quad * 4 + reg][16 + r16] = f2bf(O1[reg]);
    }
    {
        int r = lane >> 2, c0 = (lane & 3) * 8;
        short8 v = *(const short8*)&Pl[w][r][c0];
        int q = w * 16 + r;
        size_t m = (size_t)((n * HH + i0 + (q >> 3)) * WW + j0 + (q & 7));
        *(short8*)(outp + m * CC + h * DD + c0) = v;
    }
}

// ---------------- fused tail: 16 rows/block, 8 waves (512 thr) --------
__global__ __launch_bounds__(512, 6) void tail_kernel(
    const BF* __restrict__ A, const BF* __restrict__ projT2,
    const float* __restrict__ proj_b, const float* __restrict__ x,
    const BF* __restrict__ tbuf, const float* __restrict__ glw,
    const float* __restrict__ w2, const float* __restrict__ b2,
    const BF* __restrict__ fc1T2, const float* __restrict__ fc1_b,
    const BF* __restrict__ fc2T2, const float* __restrict__ fc2_b,
    float* __restrict__ out)
{
    __shared__ __align__(16) char sarena[9216];     // xs [16][132] f32 / st [128][18] f32
    __shared__ __align__(16) BF ln2l[16][136];      // 4352 B
    __shared__ __align__(16) BF hl[16][520];        // 16640 B
    __shared__ float gl[128];
    __shared__ float S1[8][16], S2[8][16];

    float* xs = (float*)sarena;    // [p][c] stride 132
    float* st = (float*)sarena;    // [c][p] stride 18

    const int t = threadIdx.x;
    const int w = t >> 6, lane = t & 63, quad = lane >> 4, r16 = lane & 15;
    const int row0 = blockIdx.x * 16;
    const int n = row0 >> 12, p0 = row0 & 4095;
    const int col = w * 16 + r16;          // this lane's proj/fc2 column

    // ---- stage x tile: 128 c x 16 p, one float4 per thread ----
    {
        int p4 = t & 3, c = t >> 2;
        float4 v = *(const float4*)(x + (size_t)(n * CC + c) * HW + p0 + p4 * 4);
        xs[(p4 * 4 + 0) * 132 + c] = v.x; xs[(p4 * 4 + 1) * 132 + c] = v.y;
        xs[(p4 * 4 + 2) * 132 + c] = v.z; xs[(p4 * 4 + 3) * 132 + c] = v.w;
    }
    if (t < 128) gl[t] = glw[n * CC + t];

    // ---- early independent loads (overlap with proj MFMAs) ----
    float gv  = glw[n * CC + col];
    float pbv = proj_b[col];
    float tvr[4];
    #pragma unroll
    for (int reg = 0; reg < 4; reg++) {
        int lr = quad * 4 + reg;
        tvr[reg] = bf2f(tbuf[(size_t)(row0 + lr) * CC + col]);
    }

    // ---- proj: wave = 16 rows x 16 cols (no LDS dependence) ----
    floatx4 acc = {};
    const BF* arow = A + (size_t)(row0 + r16) * CC;
    #pragma unroll
    for (int ks = 0; ks < 4; ks++) {
        short8 af = *(const short8*)(arow + ks * 32 + quad * 8);
        short8 bf = *(const short8*)(projT2 + ((size_t)(ks * 128 + col)) * 32 + quad * 8);
        acc = __builtin_amdgcn_mfma_f32_16x16x32_bf16(af, bf, acc, 0, 0, 0);
    }
    __syncthreads();   // xs ready

    // ---- x2 (registers) + LN2 stats ----
    float x2r[4];
    float s1[4], s2[4];
    #pragma unroll
    for (int reg = 0; reg < 4; reg++) {
        int lr = quad * 4 + reg;
        float v = acc[reg] + pbv + xs[lr * 132 + col] + 0.02f * tvr[reg] * gv;
        x2r[reg] = v;
        s1[reg] = v; s2[reg] = v * v;
    }
    #pragma unroll
    for (int reg = 0; reg < 4; reg++) {
        #pragma unroll
        for (int off = 1; off < 16; off <<= 1) {
            s1[reg] += __shfl_xor(s1[reg], off);
            s2[reg] += __shfl_xor(s2[reg], off);
        }
    }
    if (r16 == 0) {
        #pragma unroll
        for (int reg = 0; reg < 4; reg++) {
            S1[w][quad * 4 + reg] = s1[reg];
            S2[w][quad * 4 + reg] = s2[reg];
        }
    }
    __syncthreads();
    float mu[4], rr[4];
    #pragma unroll
    for (int reg = 0; reg < 4; reg++) {
        int r = quad * 4 + reg;
        float t1 = 0.f, t2 = 0.f;
        #pragma unroll
        for (int ww = 0; ww < 8; ww++) { t1 += S1[ww][r]; t2 += S2[ww][r]; }
        mu[reg] = t1 * (1.0f / CC);
        float var = t2 * (1.0f / CC) - mu[reg] * mu[reg];
        rr[reg] = rsqrtf(var + 1e-5f);
    }
    {
        float wv = w2[col], bv2 = b2[col];
        #pragma unroll
        for (int reg = 0; reg < 4; reg++) {
            int lr = quad * 4 + reg;
            ln2l[lr][col] = f2bf((x2r[reg] - mu[reg]) * rr[reg] * wv + bv2);
        }
    }
    __syncthreads();   // ln2l ready

    // ---- fc1: wave = 16 rows x 64 cols, gelu -> hl ----
    short8 af1[4];
    #pragma unroll
    for (int ks = 0; ks < 4; ks++)
        af1[ks] = *(const short8*)&ln2l[r16][ks * 32 + quad * 8];
    floatx4 a2[4] = {};
    #pragma unroll
    for (int ks = 0; ks < 4; ks++) {
        #pragma unroll
        for (int nt = 0; nt < 4; nt++) {
            int c1col = w * 64 + nt * 16 + r16;
            short8 bf = *(const short8*)(fc1T2 + ((size_t)(ks * 512 + c1col)) * 32 + quad * 8);
            a2[nt] = __builtin_amdgcn_mfma_f32_16x16x32_bf16(af1[ks], bf, a2[nt], 0, 0, 0);
        }
    }
    #pragma unroll
    for (int nt = 0; nt < 4; nt++) {
        int c1col = w * 64 + nt * 16 + r16;
        float bv = fc1_b[c1col];
        #pragma unroll
        for (int reg = 0; reg < 4; reg++) {
            int lr = quad * 4 + reg;
            hl[lr][c1col] = f2bf(gelu_f(a2[nt][reg] + bv));
        }
    }
    __syncthreads();   // hl ready

    // ---- fc2: wave = 16 rows x 16 cols, K=512 ----
    floatx4 a3 = {};
    #pragma unroll
    for (int ks = 0; ks < 16; ks++) {
        short8 af = *(const short8*)&hl[r16][ks * 32 + quad * 8];
        short8 bf = *(const short8*)(fc2T2 + ((size_t)(ks * 128 + col)) * 32 + quad * 8);
        a3 = __builtin_amdgcn_mfma_f32_16x16x32_bf16(af, bf, a3, 0, 0, 0);
    }
    // xs reads are >=2 barriers upstream; st overlay safe without a barrier
    {
        float bv = fc2_b[col];
        #pragma unroll
        for (int reg = 0; reg < 4; reg++) {
            int lr = quad * 4 + reg;
            st[col * 18 + lr] = a3[reg] + bv + x2r[reg];
        }
    }
    __syncthreads();
    {   // coalesced NCHW store: 128 cols x 16 p, one float4 per thread
        int c = t >> 2, u4 = t & 3;
        float4 v;
        v.x = st[c * 18 + u4 * 4 + 0];
        v.y = st[c * 18 + u4 * 4 + 1];
        v.z = st[c * 18 + u4 * 4 + 2];
        v.w = st[c * 18 + u4 * 4 + 3];
        *(float4*)(out + (size_t)(n * CC + c) * HW + p0 + u4 * 4) = v;
    }
}

extern "C" void kernel_launch(void* const* d_in, const int* in_sizes, int n_in,
                              void* d_out, int out_size, void* d_ws, size_t ws_size,
                              hipStream_t stream)
{
    const float* x       = (const float*)d_in[0];
    const float* ln1_w   = (const float*)d_in[1];
    const float* ln1_b   = (const float*)d_in[2];
    const float* ln2_w   = (const float*)d_in[3];
    const float* ln2_b   = (const float*)d_in[4];
    const float* qkv_w   = (const float*)d_in[5];
    const float* qkv_b   = (const float*)d_in[6];
    const float* proj_w  = (const float*)d_in[7];
    const float* proj_b  = (const float*)d_in[8];
    const float* rpb     = (const float*)d_in[9];
    const float* conv1_w = (const float*)d_in[10];
    const float* conv1_b = (const float*)d_in[11];
    const float* conv2_w = (const float*)d_in[12];
    const float* conv2_b = (const float*)d_in[13];
    const float* ca1_w   = (const float*)d_in[14];
    const float* ca1_b   = (const float*)d_in[15];
    const float* ca2_w   = (const float*)d_in[16];
    const float* ca2_b   = (const float*)d_in[17];
    const float* fc1_w   = (const float*)d_in[18];
    const float* fc1_b   = (const float*)d_in[19];
    const float* fc2_w   = (const float*)d_in[20];
    const float* fc2_b   = (const float*)d_in[21];
    float* out = (float*)d_out;

    char* ws = (char*)d_ws;
    BF*    xn_bf   = (BF*)(ws);                  // M*128*2 = 4 MB
    BF*    qkv_bf  = (BF*)(ws + 4194304);        // M*384*2 = 12 MB
    BF*    t_bf    = (BF*)(ws + 16777216);       // M*128*2 = 4 MB
    BF*    na_bf   = (BF*)(ws + 20971520);       // M*128*2 = 4 MB
    float* part    = (float*)(ws + 25165824);    // 2 KB
    BF*    qkvT    = (BF*)(ws + 25167872);       // 98304 B
    BF*    c1T     = (BF*)(ws + 25266176);       // 8192 B
    BF*    c2T     = (BF*)(ws + 25274368);       // 8192 B
    BF*    projT2  = (BF*)(ws + 25282560);       // 32768 B
    BF*    fc1T2   = (BF*)(ws + 25315328);       // 131072 B
    BF*    fc2T2   = (BF*)(ws + 25446400);       // 131072 B
    float* glw     = (float*)(ws + 25577472);    // 2 KB   CA gate [4][128]

    // 1. weight prep (blocks 0..127, first) + LN1 (1024 x 16px)
    ln1t_kernel<<<1152, 256, 0, stream>>>(x, ln1_w, ln1_b, xn_bf, part,
        qkv_w, conv1_w, conv2_w, proj_w, fc1_w, fc2_w,
        qkvT, c1T, c2T, projT2, fc1T2, fc2T2);
    // 2. conv-MLP (256 blocks, first) + qkv GEMM (1536 blocks), no staging
    phase2<<<1792, 256, 0, stream>>>(xn_bf, qkvT, qkv_b, qkv_bf,
                                     c1T, conv1_b, c2T, conv2_b, t_bf, part);
    // 3. windowed-Pl MFMA neighborhood attention (4 blocks/CU) + CA MLP
    na_mfma_kernel<<<1025, 256, 0, stream>>>(qkv_bf, rpb, na_bf,
                                             part, ca1_w, ca1_b, ca2_w, ca2_b, glw);
    // 4. fused tail: 16 rows/block, grid 1024, 512 threads (8 waves)
    tail_kernel<<<1024, 512, 0, stream>>>(na_bf, projT2, proj_b, x, t_bf, glw,
                                          ln2_w, ln2_b, fc1T2, fc1_b,
                                          fc2T2, fc2_b, out);
}

// Round 11
// 154.941 us; speedup vs baseline: 1.0572x; 1.0572x over previous
//
#include <hip/hip_runtime.h>
#include <hip/hip_bf16.h>
#include <math.h>

#define NB 4
#define CC 128
#define HH 64
#define WW 64
#define HEADS 4
#define KS 7
#define DD 32
#define HW 4096
#define MTOT 16384   // NB*HW

typedef unsigned short BF;
typedef short short8 __attribute__((ext_vector_type(8)));
typedef float floatx4 __attribute__((ext_vector_type(4)));

__device__ __forceinline__ float gelu_f(float x) {
    return 0.5f * x * (1.0f + erff(x * 0.70710678118654752440f));
}

__device__ __forceinline__ BF f2bf(float f) {
    union { float f; unsigned u; } a; a.f = f;
    unsigned u = a.u;
    unsigned r = u + 0x7FFFu + ((u >> 16) & 1u);   // RNE
    return (BF)(r >> 16);
}

__device__ __forceinline__ float bf2f(BF v) {
    return __uint_as_float(((unsigned)v) << 16);
}

#define LDK 40      // padded LDS row, K=32 tiles (bf16)
#define LDK128 136  // padded LDS row, K=128 tiles (bf16)

// ---------------- LN1 (16 px/block, 1024 blocks) + weight prep --------
// R9 best-measured configuration (155.27 us): LN split 1024x16px,
// prep blocks trailing (R10's prep-first + staging removal regressed
// to 163.8 -- the LDS staging was load-bearing; exact revert).
__global__ __launch_bounds__(256) void ln1t_kernel(
    const float* __restrict__ x, const float* __restrict__ w,
    const float* __restrict__ b, BF* __restrict__ out,
    float* __restrict__ part,
    const float* __restrict__ qkv_w, const float* __restrict__ conv1_w,
    const float* __restrict__ conv2_w, const float* __restrict__ proj_w,
    const float* __restrict__ fc1_w, const float* __restrict__ fc2_w,
    BF* __restrict__ qkvT, BF* __restrict__ c1T, BF* __restrict__ c2T,
    BF* __restrict__ projT2, BF* __restrict__ fc1T2, BF* __restrict__ fc2T2)
{
    const int blk = blockIdx.x;
    const int t  = threadIdx.x;

    if (blk >= 1024) {   // ---- weight prep (one-time, 204800 elems) ----
        for (int idx = (blk - 1024) * 256 + t; idx < 204800; idx += 32768) {
            if (idx < 49152) {                    // qkvT [384][128]
                int l = idx, n = l >> 7, k = l & 127;
                qkvT[l] = f2bf(qkv_w[k * 384 + n]);
            } else if (idx < 53248) {             // c1T [32][128]
                int l = idx - 49152, n = l >> 7, k = l & 127;
                c1T[l] = f2bf(conv1_w[k * 32 + n]);
            } else if (idx < 57344) {             // c2T [128][32]
                int l = idx - 53248, n = l >> 5, k = l & 31;
                c2T[l] = f2bf(conv2_w[k * 128 + n]);
            } else if (idx < 73728) {             // projT2 [4][128][32]
                int l = idx - 57344, kk = l & 31, n = (l >> 5) & 127, ks = l >> 12;
                projT2[l] = f2bf(proj_w[(ks * 32 + kk) * 128 + n]);
            } else if (idx < 139264) {            // fc1T2 [4][512][32]
                int l = idx - 73728, kk = l & 31, n = (l >> 5) & 511, ks = l >> 14;
                fc1T2[l] = f2bf(fc1_w[(ks * 32 + kk) * 512 + n]);
            } else {                              // fc2T2 [16][128][32]
                int l = idx - 139264, kk = l & 31, n = (l >> 5) & 127, ks = l >> 12;
                fc2T2[l] = f2bf(fc2_w[(ks * 32 + kk) * 128 + n]);
            }
        }
        return;
    }

    __shared__ float xt[128][17];
    __shared__ float mus[16], rss[16];
    const int n  = blk >> 8;
    const int p0 = (blk & 255) * 16;
    if (blk < 4 && t < 128) part[blk * CC + t] = 0.f;   // zero CA partials

    {   // stage [128 c][16 p]: 2 float4 per thread
        int c = t >> 1, pp0 = (t & 1) * 8;
        const float* src = x + (size_t)(n * CC + c) * HW + p0 + pp0;
        float4 v0 = *(const float4*)(src);
        float4 v1 = *(const float4*)(src + 4);
        xt[c][pp0 + 0] = v0.x; xt[c][pp0 + 1] = v0.y;
        xt[c][pp0 + 2] = v0.z; xt[c][pp0 + 3] = v0.w;
        xt[c][pp0 + 4] = v1.x; xt[c][pp0 + 5] = v1.y;
        xt[c][pp0 + 6] = v1.z; xt[c][pp0 + 7] = v1.w;
    }
    __syncthreads();
    {   // stats: 16 threads per pixel, 8 channels each
        int pp2 = t >> 4, cb = t & 15;
        float s = 0.f;
        #pragma unroll
        for (int u = 0; u < 8; u++) s += xt[cb + u * 16][pp2];
        s += __shfl_xor(s, 1); s += __shfl_xor(s, 2);
        s += __shfl_xor(s, 4); s += __shfl_xor(s, 8);
        float mu = s * (1.0f / CC);
        float v = 0.f;
        #pragma unroll
        for (int u = 0; u < 8; u++) { float d = xt[cb + u * 16][pp2] - mu; v += d * d; }
        v += __shfl_xor(v, 1); v += __shfl_xor(v, 2);
        v += __shfl_xor(v, 4); v += __shfl_xor(v, 8);
        if (cb == 0) { mus[pp2] = mu; rss[pp2] = rsqrtf(v * (1.0f / CC) + 1e-5f); }
    }
    __syncthreads();
    {   // apply: one short8 per thread (16 px x 16 thr)
        int pp2 = t >> 4, c0 = (t & 15) * 8;
        float mu = mus[pp2], rs = rss[pp2];
        int m = n * HW + p0 + pp2;
        short8 o;
        #pragma unroll
        for (int u = 0; u < 8; u++)
            o[u] = (short)f2bf((xt[c0 + u][pp2] - mu) * rs * w[c0 + u] + b[c0 + u]);
        *(short8*)(out + (size_t)m * CC + c0) = o;
    }
}

// ---------------- phase2: conv-MLP first, then qkv GEMM ---------------
// Conv blocks (3 barrier-phases, longest path) are bid<256 so they
// DISPATCH FIRST and hide under the 1536-block qkv supply. qkv: 64-row
// blocks, cooperative Bl LDS staging (load-bearing: R10's removal cost
// +8.5us), per-wave LDS transpose epilogue -> short8 coalesced stores.
__global__ __launch_bounds__(256) void phase2(
    const BF* __restrict__ xn, const BF* __restrict__ qkvT,
    const float* __restrict__ qkv_b, BF* __restrict__ qkv_out,
    const BF* __restrict__ c1T, const float* __restrict__ b1,
    const BF* __restrict__ c2T, const float* __restrict__ b2,
    BF* __restrict__ tout, float* __restrict__ part)
{
    __shared__ __align__(16) char smem[26624];
    const int bid = blockIdx.x;
    const int t = threadIdx.x;
    const int w = t >> 6, lane = t & 63, q = lane >> 4, r16 = lane & 15;

    if (bid >= 256) {
        const int qb = bid - 256;
        BF* Bl = (BF*)smem;                  // [64][LDK128] 17408 B
        BF* Ct = (BF*)(smem + 17408);        // [64][72]      9216 B (per-wave 16-row regions)
        const int col0 = (qb % 6) * 64;
        const int row0 = (qb / 6) * 64;
        {
            int nn = t >> 2;
            int kk = (t & 3) * 32;
            const BF* src = qkvT + (size_t)(col0 + nn) * 128 + kk;
            #pragma unroll
            for (int u = 0; u < 4; u++)
                *(uint4*)(Bl + nn * LDK128 + kk + u * 8) = *(const uint4*)(src + u * 8);
        }
        __syncthreads();
        floatx4 acc[4] = {};
        const BF* arow = xn + (size_t)(row0 + w * 16 + r16) * CC;
        #pragma unroll
        for (int ks = 0; ks < 4; ks++) {
            short8 af = *(const short8*)(arow + ks * 32 + q * 8);
            #pragma unroll
            for (int nt = 0; nt < 4; nt++) {
                short8 bf = *(const short8*)(Bl + (nt * 16 + r16) * LDK128 + ks * 32 + q * 8);
                acc[nt] = __builtin_amdgcn_mfma_f32_16x16x32_bf16(af, bf, acc[nt], 0, 0, 0);
            }
        }
        // stage wave's 16x64 tile in its own Ct region (no block barrier)
        #pragma unroll
        for (int nt = 0; nt < 4; nt++) {
            int col = col0 + nt * 16 + r16;
            float bv = qkv_b[col];
            #pragma unroll
            for (int reg = 0; reg < 4; reg++)
                Ct[(w * 16 + q * 4 + reg) * 72 + nt * 16 + r16] = f2bf(acc[nt][reg] + bv);
        }
        // coalesced short8 stores: 2 per thread (was 32 scalar 2B)
        #pragma unroll
        for (int u2 = 0; u2 < 2; u2++) {
            int r = u2 * 8 + (lane >> 3), c0 = (lane & 7) * 8;
            short8 v = *(const short8*)(Ct + (w * 16 + r) * 72 + c0);
            *(short8*)(qkv_out + (size_t)(row0 + w * 16 + r) * 384 + col0 + c0) = v;
        }
        return;
    }
    // ---- conv branch (bid < 256) ----
    BF*    W1l = (BF*)smem;                  // [32][LDK128]  8704 B
    BF*    W2l = (BF*)(smem + 8704);         // [128][LDK]   10240 B
    BF*    Hl  = (BF*)(smem + 18944);        // [64][LDK]     5120 B
    float* red = (float*)(smem + 24064);     // [4][128]      2048 B
    const int row0 = bid * 64;
    {
        #pragma unroll
        for (int it = 0; it < 2; it++) {
            int idx = it * 256 + t;
            int nn = idx >> 4, u = idx & 15;
            *(uint4*)(W1l + nn * LDK128 + u * 8) = *(const uint4*)(c1T + nn * 128 + u * 8);
        }
    }
    {
        #pragma unroll
        for (int it = 0; it < 2; it++) {
            int idx = it * 256 + t;
            int nn = idx >> 2, u = idx & 3;
            *(uint4*)(W2l + nn * LDK + u * 8) = *(const uint4*)(c2T + nn * 32 + u * 8);
        }
    }
    __syncthreads();
    floatx4 a1[2] = {};
    const BF* arow = xn + (size_t)(row0 + w * 16 + r16) * CC;
    #pragma unroll
    for (int ks = 0; ks < 4; ks++) {
        short8 af = *(const short8*)(arow + ks * 32 + q * 8);
        #pragma unroll
        for (int nt = 0; nt < 2; nt++) {
            short8 bf = *(const short8*)(W1l + (nt * 16 + r16) * LDK128 + ks * 32 + q * 8);
            a1[nt] = __builtin_amdgcn_mfma_f32_16x16x32_bf16(af, bf, a1[nt], 0, 0, 0);
        }
    }
    #pragma unroll
    for (int nt = 0; nt < 2; nt++) {
        int col = nt * 16 + r16;
        float bv = b1[col];
        #pragma unroll
        for (int reg = 0; reg < 4; reg++)
            Hl[(w * 16 + q * 4 + reg) * LDK + col] = f2bf(gelu_f(a1[nt][reg] + bv));
    }
    __syncthreads();
    floatx4 a2[8] = {};
    short8 af2 = *(const short8*)(Hl + (w * 16 + r16) * LDK + q * 8);
    #pragma unroll
    for (int nt = 0; nt < 8; nt++) {
        short8 bf = *(const short8*)(W2l + (nt * 16 + r16) * LDK + q * 8);
        a2[nt] = __builtin_amdgcn_mfma_f32_16x16x32_bf16(af2, bf, a2[nt], 0, 0, 0);
    }
    #pragma unroll
    for (int nt = 0; nt < 8; nt++) {
        int col = nt * 16 + r16;
        float bv = b2[col];
        float s = 0.f;
        #pragma unroll
        for (int reg = 0; reg < 4; reg++) {
            int row = row0 + w * 16 + q * 4 + reg;
            float v = a2[nt][reg] + bv;
            tout[(size_t)row * CC + col] = f2bf(v);
            s += v;
        }
        s += __shfl_xor(s, 16);
        s += __shfl_xor(s, 32);
        if (lane < 16) red[w * 128 + col] = s;
    }
    __syncthreads();
    if (t < 128) {
        float cs = red[t] + red[128 + t] + red[256 + t] + red[384 + t];
        atomicAdd(&part[(row0 >> 12) * CC + t], cs);
    }
}

// ---------------- MFMA neighborhood attention (windowed Pl) -----------
// K/Q direct from L2. Pl stores only the wave's 10-key-tile window
// relative to pbase = kt0 & ~1. LDS 37.1 KB => 4 blocks/CU.
// Block 1024 (extra): per-image CA micro-MLP (gl[4][128]).
__global__ __launch_bounds__(256, 4) void na_mfma_kernel(
    const BF* __restrict__ qkv, const float* __restrict__ rpb,
    BF* __restrict__ outp,
    const float* __restrict__ part,
    const float* __restrict__ ca1_w, const float* __restrict__ ca1_b,
    const float* __restrict__ ca2_w, const float* __restrict__ ca2_b,
    float* __restrict__ glw)
{
    __shared__ __align__(16) BF Vt[32][232];        // 14848 B
    __shared__ __align__(16) BF Pl[4][16][168];     // 21504 B (10-tile window)
    __shared__ float rb[169];

    const int b = blockIdx.x;
    const int t = threadIdx.x;

    if (b == 1024) {   // ---- CA micro-MLP, once per launch ----
        float* gsm = (float*)Vt;    // [4][128] f32, aliases Vt
        float* h1s = (float*)Pl;    // [28] f32, aliases Pl
        if (t < 128) {
            #pragma unroll
            for (int nn = 0; nn < 4; nn++)
                gsm[nn * 128 + t] = part[nn * CC + t] * (1.0f / HW);
        }
        __syncthreads();
        if (t < 224) {              // 28 (n,r) pairs x 8 lanes each
            int pair = t >> 3, s = t & 7;
            int nn = pair / 7, r = pair % 7;
            float a = 0.f;
            #pragma unroll
            for (int k = 0; k < 16; k++)
                a += gsm[nn * 128 + s + k * 8] * ca1_w[(s + k * 8) * 7 + r];
            a += __shfl_xor(a, 1); a += __shfl_xor(a, 2); a += __shfl_xor(a, 4);
            if (s == 0) h1s[pair] = fmaxf(a + ca1_b[r], 0.f);
        }
        __syncthreads();
        if (t < 128) {
            #pragma unroll
            for (int nn = 0; nn < 4; nn++) {
                float o = ca2_b[t];
                #pragma unroll
                for (int r = 0; r < 7; r++) o += h1s[nn * 7 + r] * ca2_w[r * 128 + t];
                glw[nn * CC + t] = 1.0f / (1.0f + expf(-o));
            }
        }
        return;
    }

    const int h = b & 3;
    const int tile = b >> 2;
    const int n = tile >> 6;
    const int ti = (tile >> 3) & 7, tj = tile & 7;
    const int w = t >> 6, lane = t & 63, quad = lane >> 4, r16 = lane & 15;
    const int i0 = ti * 8, j0 = tj * 8;
    const int wi0 = max(i0 - 3, 0), wj0 = max(j0 - 3, 0);
    const int R  = min(wi0 + 13, 63) - wi0 + 1;
    const int Rj = min(wj0 + 13, 63) - wj0 + 1;

    // ---- stage rpb + V (transposed); no barrier yet ----
    if (t < 169) rb[t] = rpb[h * 169 + t];
    for (int idx = t; idx < 896; idx += 256) {
        int key = idx >> 2, ch = idx & 3;
        int kr = key >> 4, kc = key & 15;
        if (kr < R && kc < Rj) {
            size_t pix = (size_t)((n * HH + wi0 + kr) * WW + wj0 + kc);
            uint4 v = *(const uint4*)(qkv + pix * 384 + 256 + h * DD + ch * 8);
            const BF* pv = (const BF*)&v;
            #pragma unroll
            for (int u = 0; u < 8; u++) Vt[ch * 8 + u][key] = pv[u];
        } else {
            #pragma unroll
            for (int u = 0; u < 8; u++) Vt[ch * 8 + u][key] = 0;
        }
    }

    // wave's first pixel row -> pruned k-tile base
    const int kt0 = min(max(i0 + 2 * w - 3, 0), HH - KS) - wi0;
    const int odd = kt0 & 1;     // P window offset: pbase = kt0 - odd

    int oi[4], cok[4], bj0[4], ai_[4];
    #pragma unroll
    for (int reg = 0; reg < 4; reg++) {
        int q = w * 16 + quad * 4 + reg;
        int i = i0 + (q >> 3), j = j0 + (q & 7);
        int ni = min(max(i - 3, 0), HH - KS), nj = min(max(j - 3, 0), WW - KS);
        oi[reg]  = ni - wi0;
        ai_[reg] = ni - i + 6;
        int dc = r16 - (nj - wj0);
        cok[reg] = ((unsigned)dc < 7u) ? 1 : 0;
        bj0[reg] = min(max(dc + (nj - j + 6), 0), 12);
    }

    // ---- Q fragment direct from L2 ----
    const int qr = w * 16 + r16;
    short8 aq = *(const short8*)(qkv
        + (size_t)((n * HH + i0 + (qr >> 3)) * WW + j0 + (qr & 7)) * 384
        + h * DD + quad * 8);

    // ---- QK^T: K fragments direct from L2 (kr=kt0+jt uniform, kc=r16) ----
    floatx4 S[8];
    const bool colok = (r16 < Rj);
    #pragma unroll
    for (int jt = 0; jt < 8; jt++) {
        short8 bk = {0, 0, 0, 0, 0, 0, 0, 0};
        if ((kt0 + jt) < R && colok) {
            bk = *(const short8*)(qkv
                + (size_t)((n * HH + wi0 + kt0 + jt) * WW + wj0 + r16) * 384
                + 128 + h * DD + quad * 8);
        }
        floatx4 z = {0.f, 0.f, 0.f, 0.f};
        S[jt] = __builtin_amdgcn_mfma_f32_16x16x32_bf16(aq, bk, z, 0, 0, 0);
    }
    __syncthreads();   // Vt + rb ready (drained while MFMAs ran)

    const float scale = 0.17677669529663688110f;
    #pragma unroll
    for (int jt = 0; jt < 8; jt++) {
        #pragma unroll
        for (int reg = 0; reg < 4; reg++) {
            int dr = kt0 + jt - oi[reg];
            bool ok = ((unsigned)dr < 7u) && cok[reg];
            int bi = min(max(dr + ai_[reg], 0), 12);
            float bias = rb[bi * 13 + bj0[reg]];
            S[jt][reg] = ok ? fmaf(S[jt][reg], scale, bias) : -1e30f;
        }
    }
    float rinv[4];
    #pragma unroll
    for (int reg = 0; reg < 4; reg++) {
        float m = S[0][reg];
        #pragma unroll
        for (int jt = 1; jt < 8; jt++) m = fmaxf(m, S[jt][reg]);
        m = fmaxf(m, __shfl_xor(m, 1));
        m = fmaxf(m, __shfl_xor(m, 2));
        m = fmaxf(m, __shfl_xor(m, 4));
        m = fmaxf(m, __shfl_xor(m, 8));
        float s = 0.f;
        #pragma unroll
        for (int jt = 0; jt < 8; jt++) {
            float e = __expf(S[jt][reg] - m);
            S[jt][reg] = e;
            s += e;
        }
        s += __shfl_xor(s, 1);
        s += __shfl_xor(s, 2);
        s += __shfl_xor(s, 4);
        s += __shfl_xor(s, 8);
        rinv[reg] = 1.0f / s;
    }
    // Pl is per-wave private; window-relative column (jt+odd)*16 + r16
    #pragma unroll
    for (int jt = 0; jt < 8; jt++)
        #pragma unroll
        for (int reg = 0; reg < 4; reg++)
            Pl[w][quad * 4 + reg][(jt + odd) * 16 + r16] = f2bf(S[jt][reg] * rinv[reg]);
    if (odd) {   // zero boundary tiles 0 and 9 read by the extra PV chunk
        #pragma unroll
        for (int reg = 0; reg < 4; reg++) {
            Pl[w][quad * 4 + reg][r16]            = 0;
            Pl[w][quad * 4 + reg][144 + r16]      = 0;
        }
    }

    const int ks0 = kt0 >> 1;
    const int nch = 4 + odd;
    floatx4 O0 = {0.f, 0.f, 0.f, 0.f}, O1 = {0.f, 0.f, 0.f, 0.f};
    #pragma unroll
    for (int c2 = 0; c2 < 5; c2++) {
        if (c2 < nch) {
            int ks = ks0 + c2;   // absolute (for Vt); Pl col is relative
            short8 ap = *(const short8*)&Pl[w][r16][c2 * 32 + quad * 8];
            short8 b0 = *(const short8*)&Vt[r16][ks * 32 + quad * 8];
            short8 b1 = *(const short8*)&Vt[16 + r16][ks * 32 + quad * 8];
            O0 = __builtin_amdgcn_mfma_f32_16x16x32_bf16(ap, b0, O0, 0, 0, 0);
            O1 = __builtin_amdgcn_mfma_f32_16x16x32_bf16(ap, b1, O1, 0, 0, 0);
        }
    }
    // ---- coalesced output: stage 16x32 tile in Pl[w] (dead after PV) ----
    #pragma unroll
    for (int reg = 0; reg < 4; reg++) {
        Pl[w][quad * 4 + reg][r16]      = f2bf(O0[reg]);
        Pl[w][quad * 4 + reg][16 + r16] = f2bf(O1[reg]);
    }
    {
        int r = lane >> 2, c0 = (lane & 3) * 8;
        short8 v = *(const short8*)&Pl[w][r][c0];
        int q = w * 16 + r;
        size_t m = (size_t)((n * HH + i0 + (q >> 3)) * WW + j0 + (q & 7));
        *(short8*)(outp + m * CC + h * DD + c0) = v;
    }
}

// ---------------- fused tail: 16 rows/block, 8 waves (512 thr) --------
__global__ __launch_bounds__(512, 6) void tail_kernel(
    const BF* __restrict__ A, const BF* __restrict__ projT2,
    const float* __restrict__ proj_b, const float* __restrict__ x,
    const BF* __restrict__ tbuf, const float* __restrict__ glw,
    const float* __restrict__ w2, const float* __restrict__ b2,
    const BF* __restrict__ fc1T2, const float* __restrict__ fc1_b,
    const BF* __restrict__ fc2T2, const float* __restrict__ fc2_b,
    float* __restrict__ out)
{
    __shared__ __align__(16) char sarena[9216];     // xs [16][132] f32 / st [128][18] f32
    __shared__ __align__(16) BF ln2l[16][136];      // 4352 B
    __shared__ __align__(16) BF hl[16][520];        // 16640 B
    __shared__ float gl[128];
    __shared__ float S1[8][16], S2[8][16];

    float* xs = (float*)sarena;    // [p][c] stride 132
    float* st = (float*)sarena;    // [c][p] stride 18

    const int t = threadIdx.x;
    const int w = t >> 6, lane = t & 63, quad = lane >> 4, r16 = lane & 15;
    const int row0 = blockIdx.x * 16;
    const int n = row0 >> 12, p0 = row0 & 4095;
    const int col = w * 16 + r16;          // this lane's proj/fc2 column

    // ---- stage x tile: 128 c x 16 p, one float4 per thread ----
    {
        int p4 = t & 3, c = t >> 2;
        float4 v = *(const float4*)(x + (size_t)(n * CC + c) * HW + p0 + p4 * 4);
        xs[(p4 * 4 + 0) * 132 + c] = v.x; xs[(p4 * 4 + 1) * 132 + c] = v.y;
        xs[(p4 * 4 + 2) * 132 + c] = v.z; xs[(p4 * 4 + 3) * 132 + c] = v.w;
    }
    if (t < 128) gl[t] = glw[n * CC + t];

    // ---- early independent loads (overlap with proj MFMAs) ----
    float gv  = glw[n * CC + col];
    float pbv = proj_b[col];
    float tvr[4];
    #pragma unroll
    for (int reg = 0; reg < 4; reg++) {
        int lr = quad * 4 + reg;
        tvr[reg] = bf2f(tbuf[(size_t)(row0 + lr) * CC + col]);
    }

    // ---- proj: wave = 16 rows x 16 cols (no LDS dependence) ----
    floatx4 acc = {};
    const BF* arow = A + (size_t)(row0 + r16) * CC;
    #pragma unroll
    for (int ks = 0; ks < 4; ks++) {
        short8 af = *(const short8*)(arow + ks * 32 + quad * 8);
        short8 bf = *(const short8*)(projT2 + ((size_t)(ks * 128 + col)) * 32 + quad * 8);
        acc = __builtin_amdgcn_mfma_f32_16x16x32_bf16(af, bf, acc, 0, 0, 0);
    }
    __syncthreads();   // xs ready

    // ---- x2 (registers) + LN2 stats ----
    float x2r[4];
    float s1[4], s2[4];
    #pragma unroll
    for (int reg = 0; reg < 4; reg++) {
        int lr = quad * 4 + reg;
        float v = acc[reg] + pbv + xs[lr * 132 + col] + 0.02f * tvr[reg] * gv;
        x2r[reg] = v;
        s1[reg] = v; s2[reg] = v * v;
    }
    #pragma unroll
    for (int reg = 0; reg < 4; reg++) {
        #pragma unroll
        for (int off = 1; off < 16; off <<= 1) {
            s1[reg] += __shfl_xor(s1[reg], off);
            s2[reg] += __shfl_xor(s2[reg], off);
        }
    }
    if (r16 == 0) {
        #pragma unroll
        for (int reg = 0; reg < 4; reg++) {
            S1[w][quad * 4 + reg] = s1[reg];
            S2[w][quad * 4 + reg] = s2[reg];
        }
    }
    __syncthreads();
    float mu[4], rr[4];
    #pragma unroll
    for (int reg = 0; reg < 4; reg++) {
        int r = quad * 4 + reg;
        float t1 = 0.f, t2 = 0.f;
        #pragma unroll
        for (int ww = 0; ww < 8; ww++) { t1 += S1[ww][r]; t2 += S2[ww][r]; }
        mu[reg] = t1 * (1.0f / CC);
        float var = t2 * (1.0f / CC) - mu[reg] * mu[reg];
        rr[reg] = rsqrtf(var + 1e-5f);
    }
    {
        float wv = w2[col], bv2 = b2[col];
        #pragma unroll
        for (int reg = 0; reg < 4; reg++) {
            int lr = quad * 4 + reg;
            ln2l[lr][col] = f2bf((x2r[reg] - mu[reg]) * rr[reg] * wv + bv2);
        }
    }
    __syncthreads();   // ln2l ready

    // ---- fc1: wave = 16 rows x 64 cols, gelu -> hl ----
    short8 af1[4];
    #pragma unroll
    for (int ks = 0; ks < 4; ks++)
        af1[ks] = *(const short8*)&ln2l[r16][ks * 32 + quad * 8];
    floatx4 a2[4] = {};
    #pragma unroll
    for (int ks = 0; ks < 4; ks++) {
        #pragma unroll
        for (int nt = 0; nt < 4; nt++) {
            int c1col = w * 64 + nt * 16 + r16;
            short8 bf = *(const short8*)(fc1T2 + ((size_t)(ks * 512 + c1col)) * 32 + quad * 8);
            a2[nt] = __builtin_amdgcn_mfma_f32_16x16x32_bf16(af1[ks], bf, a2[nt], 0, 0, 0);
        }
    }
    #pragma unroll
    for (int nt = 0; nt < 4; nt++) {
        int c1col = w * 64 + nt * 16 + r16;
        float bv = fc1_b[c1col];
        #pragma unroll
        for (int reg = 0; reg < 4; reg++) {
            int lr = quad * 4 + reg;
            hl[lr][c1col] = f2bf(gelu_f(a2[nt][reg] + bv));
        }
    }
    __syncthreads();   // hl ready

    // ---- fc2: wave = 16 rows x 16 cols, K=512 ----
    floatx4 a3 = {};
    #pragma unroll
    for (int ks = 0; ks < 16; ks++) {
        short8 af = *(const short8*)&hl[r16][ks * 32 + quad * 8];
        short8 bf = *(const short8*)(fc2T2 + ((size_t)(ks * 128 + col)) * 32 + quad * 8);
        a3 = __builtin_amdgcn_mfma_f32_16x16x32_bf16(af, bf, a3, 0, 0, 0);
    }
    // xs reads are >=2 barriers upstream; st overlay safe without a barrier
    {
        float bv = fc2_b[col];
        #pragma unroll
        for (int reg = 0; reg < 4; reg++) {
            int lr = quad * 4 + reg;
            st[col * 18 + lr] = a3[reg] + bv + x2r[reg];
        }
    }
    __syncthreads();
    {   // coalesced NCHW store: 128 cols x 16 p, one float4 per thread
        int c = t >> 2, u4 = t & 3;
        float4 v;
        v.x = st[c * 18 + u4 * 4 + 0];
        v.y = st[c * 18 + u4 * 4 + 1];
        v.z = st[c * 18 + u4 * 4 + 2];
        v.w = st[c * 18 + u4 * 4 + 3];
        *(float4*)(out + (size_t)(n * CC + c) * HW + p0 + u4 * 4) = v;
    }
}

extern "C" void kernel_launch(void* const* d_in, const int* in_sizes, int n_in,
                              void* d_out, int out_size, void* d_ws, size_t ws_size,
                              hipStream_t stream)
{
    const float* x       = (const float*)d_in[0];
    const float* ln1_w   = (const float*)d_in[1];
    const float* ln1_b   = (const float*)d_in[2];
    const float* ln2_w   = (const float*)d_in[3];
    const float* ln2_b   = (const float*)d_in[4];
    const float* qkv_w   = (const float*)d_in[5];
    const float* qkv_b   = (const float*)d_in[6];
    const float* proj_w  = (const float*)d_in[7];
    const float* proj_b  = (const float*)d_in[8];
    const float* rpb     = (const float*)d_in[9];
    const float* conv1_w = (const float*)d_in[10];
    const float* conv1_b = (const float*)d_in[11];
    const float* conv2_w = (const float*)d_in[12];
    const float* conv2_b = (const float*)d_in[13];
    const float* ca1_w   = (const float*)d_in[14];
    const float* ca1_b   = (const float*)d_in[15];
    const float* ca2_w   = (const float*)d_in[16];
    const float* ca2_b   = (const float*)d_in[17];
    const float* fc1_w   = (const float*)d_in[18];
    const float* fc1_b   = (const float*)d_in[19];
    const float* fc2_w   = (const float*)d_in[20];
    const float* fc2_b   = (const float*)d_in[21];
    float* out = (float*)d_out;

    char* ws = (char*)d_ws;
    BF*    xn_bf   = (BF*)(ws);                  // M*128*2 = 4 MB
    BF*    qkv_bf  = (BF*)(ws + 4194304);        // M*384*2 = 12 MB
    BF*    t_bf    = (BF*)(ws + 16777216);       // M*128*2 = 4 MB
    BF*    na_bf   = (BF*)(ws + 20971520);       // M*128*2 = 4 MB
    float* part    = (float*)(ws + 25165824);    // 2 KB
    BF*    qkvT    = (BF*)(ws + 25167872);       // 98304 B
    BF*    c1T     = (BF*)(ws + 25266176);       // 8192 B
    BF*    c2T     = (BF*)(ws + 25274368);       // 8192 B
    BF*    projT2  = (BF*)(ws + 25282560);       // 32768 B
    BF*    fc1T2   = (BF*)(ws + 25315328);       // 131072 B
    BF*    fc2T2   = (BF*)(ws + 25446400);       // 131072 B
    float* glw     = (float*)(ws + 25577472);    // 2 KB   CA gate [4][128]

    // 1. LN1 (1024 x 16px) + one-time weight prep (blocks 1024..1151)
    ln1t_kernel<<<1152, 256, 0, stream>>>(x, ln1_w, ln1_b, xn_bf, part,
        qkv_w, conv1_w, conv2_w, proj_w, fc1_w, fc2_w,
        qkvT, c1T, c2T, projT2, fc1T2, fc2T2);
    // 2. conv-MLP (256 blocks, dispatched first) + qkv GEMM (1536 blocks)
    phase2<<<1792, 256, 0, stream>>>(xn_bf, qkvT, qkv_b, qkv_bf,
                                     c1T, conv1_b, c2T, conv2_b, t_bf, part);
    // 3. windowed-Pl MFMA neighborhood attention (4 blocks/CU) + CA MLP
    na_mfma_kernel<<<1025, 256, 0, stream>>>(qkv_bf, rpb, na_bf,
                                             part, ca1_w, ca1_b, ca2_w, ca2_b, glw);
    // 4. fused tail: 16 rows/block, grid 1024, 512 threads (8 waves)
    tail_kernel<<<1024, 512, 0, stream>>>(na_bf, projT2, proj_b, x, t_bf, glw,
                                          ln2_w, ln2_b, fc1T2, fc1_b,
                                          fc2T2, fc2_b, out);
}